// Round 6
// baseline (200.855 us; speedup 1.0000x reference)
//
#include <hip/hip_runtime.h>
#include <hip/hip_bf16.h>
#include <math.h>

#define S_  2048
#define H_  1024
#define NH_ 16
#define HD_ 64
#define MM  4096            // B*S
#define NB_ 2               // batch
#define NT_ (S_ / 64)       // 32 kv tiles
#define LOG2E 1.44269504088896340736f

typedef __attribute__((ext_vector_type(8))) short bf16x8;
typedef __attribute__((ext_vector_type(4))) float f32x4;
typedef __attribute__((ext_vector_type(16))) float f32x16;
typedef __attribute__((ext_vector_type(4))) unsigned short us4;
typedef __attribute__((ext_vector_type(8))) unsigned short us8;

__device__ __forceinline__ void gld_lds16(const void* g, void* l) {
    __builtin_amdgcn_global_load_lds(
        (const __attribute__((address_space(1))) unsigned int*)g,
        (__attribute__((address_space(3))) unsigned int*)l, 16, 0, 0);
}

__device__ __forceinline__ unsigned short f2bf(float f) {
    union { float f; unsigned int u; } v; v.f = f;
    unsigned int r = v.u + 0x7FFFu + ((v.u >> 16) & 1u);
    return (unsigned short)(r >> 16);
}

// packed RNE pair convert (v_cvt_pk_bf16_f32 via HIP intrinsic)
__device__ __forceinline__ unsigned pkbf(float lo, float hi) {
    __hip_bfloat162 h = __float22bfloat162_rn(make_float2(lo, hi));
    unsigned u; __builtin_memcpy(&u, &h, 4); return u;
}

__device__ __forceinline__ float exp2_fast(float x) {
    float r; asm("v_exp_f32 %0, %1" : "=v"(r) : "v"(x)); return r;
}

// ---------------------------------------------------------------------------
// fp32 -> bf16 elementwise convert (8 elems/thread)
// ---------------------------------------------------------------------------
__global__ __launch_bounds__(256)
void cvt_bf16(const float* __restrict__ s, unsigned short* __restrict__ d, int n8)
{
    int i = blockIdx.x * 256 + threadIdx.x;
    if (i >= n8) return;
    float4 a = ((const float4*)s)[i * 2];
    float4 b = ((const float4*)s)[i * 2 + 1];
    union { unsigned u[4]; us8 v; } o;
    o.u[0] = pkbf(a.x, a.y); o.u[1] = pkbf(a.z, a.w);
    o.u[2] = pkbf(b.x, b.y); o.u[3] = pkbf(b.z, b.w);
    ((us8*)d)[i] = o.v;
}

// ---------------------------------------------------------------------------
// W [K][N] fp32 -> Wt [N][K] bf16 (tiled transpose, 4 weights via blockIdx.z)
// ---------------------------------------------------------------------------
__global__ __launch_bounds__(256)
void wtr_kernel(const float* __restrict__ W0, const float* __restrict__ W1,
                const float* __restrict__ W2, const float* __restrict__ W3,
                unsigned short* __restrict__ T0, unsigned short* __restrict__ T1,
                unsigned short* __restrict__ T2, unsigned short* __restrict__ T3)
{
    __shared__ float t[32][33];
    const float* W = blockIdx.z == 0 ? W0 : blockIdx.z == 1 ? W1 : blockIdx.z == 2 ? W2 : W3;
    unsigned short* T = blockIdx.z == 0 ? T0 : blockIdx.z == 1 ? T1 : blockIdx.z == 2 ? T2 : T3;
    const int n0 = blockIdx.x * 32, k0 = blockIdx.y * 32;
    const int tx = threadIdx.x & 31, ty = threadIdx.x >> 5;   // ty 0..7
    #pragma unroll
    for (int u = 0; u < 4; u++)
        t[ty + u * 8][tx] = W[(size_t)(k0 + ty + u * 8) * H_ + n0 + tx];
    __syncthreads();
    #pragma unroll
    for (int u = 0; u < 4; u++)
        T[(size_t)(n0 + ty + u * 8) * H_ + k0 + tx] = f2bf(t[tx][ty + u * 8]);
}

// ---------------------------------------------------------------------------
// bf16 MFMA GEMM (m97 structure), unchanged.
// EPI 0: head-split bf16 [B][NH][S][HD], value=(acc+bias)*scale
// EPI 1: transposed bf16 [B][NH][HD][S]  (for V)
// EPI 2: flat fp32 [M][N] + bias
// ---------------------------------------------------------------------------
template<int EPI>
__global__ __launch_bounds__(256)
void mfma_gemm(const unsigned short* __restrict__ A, const unsigned short* __restrict__ Bt,
               const float* __restrict__ bias, void* __restrict__ out, float scale)
{
    __shared__ __align__(16) unsigned short As[128 * 64];
    __shared__ __align__(16) unsigned short Bs[128 * 64];

    const int tid = threadIdx.x;
    const int lane = tid & 63, w = tid >> 6;
    const int lane16 = lane & 15, lg = lane >> 4;
    const int wm = w & 1, wn = w >> 1;
    const int n0 = blockIdx.x * 128, m0 = blockIdx.y * 128;

    f32x4 acc[4][4];
    #pragma unroll
    for (int m = 0; m < 4; m++)
        #pragma unroll
        for (int n = 0; n < 4; n++) acc[m][n] = (f32x4){0.f, 0.f, 0.f, 0.f};

    auto stage = [&](int kt) {
        #pragma unroll
        for (int u = 0; u < 4; u++) {
            const int seg = w * 4 + u;            // 0..15
            const int L = seg * 1024 + lane * 16; // LDS byte offset
            const int row = L >> 7;               // 0..127
            const int blk = (L >> 4) & 7;
            const int goff = kt * 64 + ((blk ^ (row & 7)) << 3);  // elements
            gld_lds16(A  + (size_t)(m0 + row) * 1024 + goff, (char*)As + L);
            gld_lds16(Bt + (size_t)(n0 + row) * 1024 + goff, (char*)Bs + L);
        }
    };

    stage(0);
    for (int kt = 0; kt < 16; kt++) {
        __syncthreads();
        #pragma unroll
        for (int ks = 0; ks < 2; ks++) {
            const int kb = ks * 64 + lg * 16;     // k byte offset within row
            bf16x8 a[4], b[4];
            #pragma unroll
            for (int m = 0; m < 4; m++) {
                const int row = wm * 64 + m * 16 + lane16;
                a[m] = *(const bf16x8*)((const char*)As + row * 128 + (kb ^ ((row & 7) << 4)));
            }
            #pragma unroll
            for (int n = 0; n < 4; n++) {
                const int row = wn * 64 + n * 16 + lane16;
                b[n] = *(const bf16x8*)((const char*)Bs + row * 128 + (kb ^ ((row & 7) << 4)));
            }
            #pragma unroll
            for (int m = 0; m < 4; m++)
                #pragma unroll
                for (int n = 0; n < 4; n++)
                    acc[m][n] = __builtin_amdgcn_mfma_f32_16x16x32_bf16(a[m], b[n], acc[m][n], 0, 0, 0);
        }
        __syncthreads();
        if (kt + 1 < 16) stage(kt + 1);
    }

    #pragma unroll
    for (int n = 0; n < 4; n++) {
        const int col = n0 + wn * 64 + n * 16 + lane16;
        const float bs = bias[col];
        #pragma unroll
        for (int m = 0; m < 4; m++) {
            const int rowb = m0 + wm * 64 + m * 16 + lg * 4;
            if (EPI == 0) {
                const int nh = col >> 6, hd = col & 63;
                #pragma unroll
                for (int j = 0; j < 4; j++) {
                    const int row = rowb + j;
                    const int bb = row >> 11, s = row & 2047;
                    ((unsigned short*)out)[((((size_t)bb * NH_ + nh) * S_ + s) << 6) + hd] =
                        f2bf((acc[m][n][j] + bs) * scale);
                }
            } else if (EPI == 1) {
                const int nh = col >> 6, hd = col & 63;
                const int bb = rowb >> 11, s = rowb & 2047;
                us4 o;
                #pragma unroll
                for (int j = 0; j < 4; j++) o[j] = f2bf(acc[m][n][j] + bs);
                *(us4*)&((unsigned short*)out)[((((size_t)bb * NH_ + nh) * HD_ + hd) << 11) + s] = o;
            } else {
                #pragma unroll
                for (int j = 0; j < 4; j++)
                    ((float*)out)[(size_t)(rowb + j) * H_ + col] = acc[m][n][j] + bs;
            }
        }
    }
}

// ---------------------------------------------------------------------------
// bf16 MFMA flash attention, swapped-QK^T + in-register softmax.
// qh: [B][NH][S][64] bf16, pre-scaled by 0.125*log2(e). kh: same layout.
// vt: [B][NH][64][S] bf16 (V^T). mask: [B][S][S] fp32. ao: [B][S][H] bf16.
// Block: 4 waves x 32 q-rows = 128-q tile; KV tiles of 64; 32x32x16 MFMA.
// St (P^T staging) aliases Qs (dead after qfrag hoist; both wave-private rows).
// Mask loads double-buffered one tile ahead (hides VMEM latency).
// ---------------------------------------------------------------------------
__global__ __launch_bounds__(256, 2)
void mfma_attn(const unsigned short* __restrict__ qh, const unsigned short* __restrict__ kh,
               const unsigned short* __restrict__ vt, const float* __restrict__ mask,
               unsigned short* __restrict__ ao)
{
    __shared__ __align__(16) unsigned short Qs[128 * 64];     // re-used as St after hoist
    __shared__ __align__(16) unsigned short Ks[2][64 * 64];
    __shared__ __align__(16) unsigned short Vs[2][64 * 64];   // [d][kv]
    unsigned short* St = Qs;                                  // [q][kv] wave-private rows

    const int tid = threadIdx.x;
    const int lane = tid & 63, wq = tid >> 6;
    const int l31 = lane & 31, lg2 = lane >> 5;
    const int qt = blockIdx.x, h = blockIdx.y, bz = blockIdx.z;
    const int q0 = qt * 128;

    const unsigned short* Qb = qh + (((size_t)(bz * NH_ + h) * S_) + q0) * HD_;
    const unsigned short* Kb = kh + ((size_t)(bz * NH_ + h) * S_) * HD_;
    const unsigned short* Vb = vt + ((size_t)(bz * NH_ + h) * HD_) * S_;
    const int qrow = wq * 32 + l31;                   // tile-local q row
    const int q = q0 + qrow;                          // global q row
    const float* Mlane = mask + ((size_t)bz * S_ + q) * S_;

    // ---- stage Q (16 KB = 4 passes of 256 thr x 16 B) ----
    #pragma unroll
    for (int u = 0; u < 4; u++) {
        const int L = u * 4096 + tid * 16;
        const int row = L >> 7, blk = (L >> 4) & 7;
        gld_lds16(Qb + (size_t)row * HD_ + ((blk ^ (row & 7)) << 3), (char*)Qs + L);
    }
    // ---- K/V tile staging (8 KB each = 2 passes each) ----
    auto stageKV = [&](int t) {
        const int buf = t & 1;
        #pragma unroll
        for (int u = 0; u < 2; u++) {
            const int L = u * 4096 + tid * 16;
            const int row = L >> 7, blk = (L >> 4) & 7;   // row: kv for K, d for V
            const int off = (blk ^ (row & 7)) << 3;
            gld_lds16(Kb + (size_t)(t * 64 + row) * HD_ + off, (char*)&Ks[buf][0] + L);
            gld_lds16(Vb + (size_t)row * S_ + t * 64 + off,    (char*)&Vs[buf][0] + L);
        }
    };
    stageKV(0);

    // ---- prologue mask loads for t=0 (consumed after QK of t=0) ----
    float4 mA[2][4], mB[2][4];
    #pragma unroll
    for (int bb = 0; bb < 2; bb++)
        #pragma unroll
        for (int m = 0; m < 4; m++)
            mA[bb][m] = *(const float4*)(Mlane + bb * 32 + m * 8 + lg2 * 4);

    __syncthreads();

    // ---- hoist Q fragments (B-operand: col q=l31, k=d contiguous 8) ----
    // reads only this wave's rows [wq*32, wq*32+32) -> no barrier needed before
    // St (same rows) is written.
    bf16x8 qfrag[4];
    #pragma unroll
    for (int s = 0; s < 4; s++)
        qfrag[s] = *(const bf16x8*)((const char*)Qs + qrow * 128 +
                                    ((s * 32 + lg2 * 16) ^ ((qrow & 7) << 4)));

    f32x16 oacc[2];
    #pragma unroll
    for (int db = 0; db < 2; db++)
        #pragma unroll
        for (int i = 0; i < 16; i++) oacc[db][i] = 0.f;
    float m_run = -3.0e38f, l_run = 0.f;

    // one kv tile; mc = this tile's (preloaded) mask, mn = next tile's buffer
    auto tile = [&](int t, float4 (&mc)[2][4], float4 (&mn)[2][4]) {
        if (t) __syncthreads();        // K/V(t) staged; all waves done with buf^1
        const int buf = t & 1;

        // ---- prefetch next K/V + next mask (consumed next tile) ----
        if (t + 1 < NT_) {
            stageKV(t + 1);
            #pragma unroll
            for (int bb = 0; bb < 2; bb++)
                #pragma unroll
                for (int m = 0; m < 4; m++)
                    mn[bb][m] = *(const float4*)(Mlane + (t + 1) * 64 + bb * 32 + m * 8 + lg2 * 4);
        }

        // ---- QK^T (S^T[kv][q]) ----
        f32x16 sc[2];
        #pragma unroll
        for (int bb = 0; bb < 2; bb++) {
            f32x16 a;
            #pragma unroll
            for (int i = 0; i < 16; i++) a[i] = 0.f;
            #pragma unroll
            for (int s = 0; s < 4; s++) {
                const int row = bb * 32 + l31;
                bf16x8 kf = *(const bf16x8*)((const char*)&Ks[buf][0] + row * 128 +
                                             ((s * 32 + lg2 * 16) ^ ((row & 7) << 4)));
                a = __builtin_amdgcn_mfma_f32_32x32x16_bf16(kf, qfrag[s], a, 0, 0, 0);
            }
            sc[bb] = a;
        }

        // ---- mask add (base-2 domain) ----
        #pragma unroll
        for (int bb = 0; bb < 2; bb++)
            #pragma unroll
            for (int m = 0; m < 4; m++) {
                sc[bb][m * 4 + 0] = fmaf(mc[bb][m].x, LOG2E, sc[bb][m * 4 + 0]);
                sc[bb][m * 4 + 1] = fmaf(mc[bb][m].y, LOG2E, sc[bb][m * 4 + 1]);
                sc[bb][m * 4 + 2] = fmaf(mc[bb][m].z, LOG2E, sc[bb][m * 4 + 2]);
                sc[bb][m * 4 + 3] = fmaf(mc[bb][m].w, LOG2E, sc[bb][m * 4 + 3]);
            }

        // ---- row max (in-register tree + cross-half via shfl) ----
        float t8[8];
        #pragma unroll
        for (int i = 0; i < 8; i++)
            t8[i] = fmaxf(fmaxf(sc[0][i], sc[0][i + 8]), fmaxf(sc[1][i], sc[1][i + 8]));
        float mloc = fmaxf(fmaxf(fmaxf(t8[0], t8[1]), fmaxf(t8[2], t8[3])),
                           fmaxf(fmaxf(t8[4], t8[5]), fmaxf(t8[6], t8[7])));
        const float mtile = fmaxf(mloc, __shfl_xor(mloc, 32, 64));

        // ---- defer-max (T13): skip rescale when growth <= 8 (base-2) ----
        float mnew;
        if (__all(mtile <= m_run + 8.f)) {
            mnew = m_run;
        } else {
            mnew = fmaxf(m_run, mtile);
            const float corr = exp2_fast(m_run - mnew);
            l_run *= corr;
            #pragma unroll
            for (int db = 0; db < 2; db++)
                #pragma unroll
                for (int i = 0; i < 16; i++) oacc[db][i] *= corr;
        }
        m_run = mnew;

        // ---- exp + row sum ----
        #pragma unroll
        for (int bb = 0; bb < 2; bb++)
            #pragma unroll
            for (int i = 0; i < 16; i++)
                sc[bb][i] = exp2_fast(sc[bb][i] - mnew);
        float s8[8];
        #pragma unroll
        for (int i = 0; i < 8; i++)
            s8[i] = (sc[0][i] + sc[0][i + 8]) + (sc[1][i] + sc[1][i + 8]);
        float sloc = ((s8[0] + s8[1]) + (s8[2] + s8[3])) + ((s8[4] + s8[5]) + (s8[6] + s8[7]));
        l_run += sloc + __shfl_xor(sloc, 32, 64);

        // ---- P^T -> LDS (wave-private rows; packed pairs via v_cvt_pk) ----
        #pragma unroll
        for (int bb = 0; bb < 2; bb++)
            #pragma unroll
            for (int r = 0; r < 16; r += 2) {
                const unsigned pv = pkbf(sc[bb][r], sc[bb][r + 1]);
                const int kvb = bb * 64 + 2 * (r & 3) + 16 * (r >> 2) + 8 * lg2;  // byte
                *(unsigned*)((char*)St + qrow * 128 + (kvb ^ ((qrow & 7) << 4))) = pv;
            }

        // ---- read P^T B-frags (same contiguous slot addressing as V) ----
        bf16x8 pfrag[4];
        #pragma unroll
        for (int s = 0; s < 4; s++)
            pfrag[s] = *(const bf16x8*)((const char*)St + qrow * 128 +
                                        ((s * 32 + lg2 * 16) ^ ((qrow & 7) << 4)));

        // ---- PV: O^T[d][q] += V^T-frag x P^T-frag ----
        #pragma unroll
        for (int s = 0; s < 4; s++)
            #pragma unroll
            for (int db = 0; db < 2; db++) {
                const int row = db * 32 + l31;
                bf16x8 vf = *(const bf16x8*)((const char*)&Vs[buf][0] + row * 128 +
                                             ((s * 32 + lg2 * 16) ^ ((row & 7) << 4)));
                oacc[db] = __builtin_amdgcn_mfma_f32_32x32x16_bf16(vf, pfrag[s], oacc[db], 0, 0, 0);
            }
    };

    for (int tt = 0; tt < NT_; tt += 2) {
        tile(tt,     mA, mB);
        tile(tt + 1, mB, mA);
    }

    // ---- epilogue: O[q][d] = O^T/l ----
    const float inv = 1.0f / l_run;
    unsigned short* aoq = ao + ((size_t)(bz * S_ + q)) * H_ + h * HD_;
    #pragma unroll
    for (int db = 0; db < 2; db++)
        #pragma unroll
        for (int m = 0; m < 4; m++) {
            us4 o = { f2bf(oacc[db][m * 4 + 0] * inv), f2bf(oacc[db][m * 4 + 1] * inv),
                      f2bf(oacc[db][m * 4 + 2] * inv), f2bf(oacc[db][m * 4 + 3] * inv) };
            *(us4*)&aoq[db * 32 + m * 8 + lg2 * 4] = o;
        }
}

// ---------------------------------------------------------------------------
extern "C" void kernel_launch(void* const* d_in, const int* in_sizes, int n_in,
                              void* d_out, int out_size, void* d_ws, size_t ws_size,
                              hipStream_t stream)
{
    (void)in_sizes; (void)n_in; (void)out_size; (void)ws_size;

    const float* query = (const float*)d_in[0];
    const float* key   = (const float*)d_in[1];
    const float* value = (const float*)d_in[2];
    const float* mask  = (const float*)d_in[3];
    const float* Wq    = (const float*)d_in[4];
    const float* bq    = (const float*)d_in[5];
    const float* Wk    = (const float*)d_in[6];
    const float* bk    = (const float*)d_in[7];
    const float* Wv    = (const float*)d_in[8];
    const float* bv    = (const float*)d_in[9];
    const float* Wo    = (const float*)d_in[10];
    const float* bo    = (const float*)d_in[11];

    unsigned short* ws = (unsigned short*)d_ws;
    const size_t MH = (size_t)MM * H_;       // 4 Mi elems
    const size_t WW = (size_t)H_ * H_;       // 1 Mi elems
    unsigned short* Xq  = ws;
    unsigned short* Xk  = Xq + MH;
    unsigned short* Xv  = Xk + MH;
    unsigned short* Wtq = Xv + MH;
    unsigned short* Wtk = Wtq + WW;
    unsigned short* Wtv = Wtk + WW;
    unsigned short* Wto = Wtv + WW;
    unsigned short* qh  = Wto + WW;
    unsigned short* kh  = qh + MH;
    unsigned short* vt  = kh + MH;
    unsigned short* ao  = vt + MH;

    const int n8 = (int)(MH / 8);            // 524288
    cvt_bf16<<<n8 / 256, 256, 0, stream>>>(query, Xq, n8);
    cvt_bf16<<<n8 / 256, 256, 0, stream>>>(key,   Xk, n8);
    cvt_bf16<<<n8 / 256, 256, 0, stream>>>(value, Xv, n8);
    wtr_kernel<<<dim3(32, 32, 4), 256, 0, stream>>>(Wq, Wk, Wv, Wo, Wtq, Wtk, Wtv, Wto);

    dim3 gg(8, 32);   // N/128, M/128
    mfma_gemm<0><<<gg, 256, 0, stream>>>(Xq, Wtq, bq, qh, 0.125f * LOG2E);
    mfma_gemm<0><<<gg, 256, 0, stream>>>(Xk, Wtk, bk, kh, 1.0f);
    mfma_gemm<1><<<gg, 256, 0, stream>>>(Xv, Wtv, bv, vt, 1.0f);

    mfma_attn<<<dim3(S_ / 128, NH_, NB_), 256, 0, stream>>>(qh, kh, vt, mask, ao);

    mfma_gemm<2><<<gg, 256, 0, stream>>>(ao, Wto, bo, d_out, 1.0f);
}